// Round 12
// baseline (22.171 us; speedup 1.0000x reference)
//
#include <hip/hip_runtime.h>

// GradLoss: mean((sobelx(t)-sobelx(o))^2) + mean((sobely(t)-sobely(o))^2)
//         = mean(sobelx(d)^2) + mean(sobely(d)^2), d = t - o   (linearity)
//
// R12 = T3/T4 at tile scale. Persistent 256 blocks x 512 thr (1/CU, 8 waves).
// Each block: 4 consecutive 16-row tiles, double-buffered LDS (144 KB).
// Per tile: issue next tile's 9 global_load_lds chunks/wave, then
//   s_waitcnt vmcnt(9)  (counted — next tile's DMAs STAY IN FLIGHT through
//   the barrier; R8's __syncthreads drained them to 0 and serialized),
//   s_barrier, compute current tile from LDS, s_barrier.
// Stage is pure DMA: rows clamped at stage, image-edge rows masked at
// compute (no VALU LDS writes -> no lgkm hazards in the stage path).
// Compute: half-based lane layout (lane*16B -> conflict-free ds_read_b128),
// seam cols 255/256 via shfl broadcast (R7-proven), 2 output rows/wave.
// Frame: two dispatches, plain partial stores, d_ws fully overwritten
// (tripwire-safe), stage2 reduces 256 partials.

#define BATCH 32
#define HH 512
#define WW 512
#define TR 16                        // output rows per tile
#define NRW (TR + 2)                 // staged rows per tile
#define TPB 512                      // 8 waves
#define NBLK 256                     // 1 block/CU, 4 tiles each

typedef const __attribute__((address_space(1))) void* gas_ptr;
typedef __attribute__((address_space(3))) void* las_ptr;

__device__ __forceinline__ void async_copy16(const float* g, float* l) {
    __builtin_amdgcn_global_load_lds((gas_ptr)(const void*)g,
                                     (las_ptr)(void*)l, 16, 0, 0);
}

__global__ __launch_bounds__(TPB) void sobel_partial_kernel(
    const float* __restrict__ out_img,
    const float* __restrict__ tgt_img,
    float* __restrict__ partials)
{
    __shared__ float tile[2][2][NRW * WW];   // [dbuf][o/t] = 144 KB
    __shared__ float wsum[TPB / 64];

    const int tid  = threadIdx.x;
    const int lane = tid & 63;
    const int wv   = tid >> 6;               // 0..7
    // XCD swizzle: each XCD gets 32 consecutive blocks (4 whole images)
    const int b    = (blockIdx.x & 7) * (NBLK / 8) + (blockIdx.x >> 3);
    const int img  = b >> 3;                 // 8 blocks per image
    const int strip0 = (b & 7) * 4;          // 4 consecutive 16-row strips
    const size_t base = (size_t)img * HH * WW;

    // ---- pure-DMA stage: 72 x 1KB chunks, 9 per wave ----
    auto STAGE = [&](int buf, int strip) {
        const int y0s = strip * TR;
        #pragma unroll
        for (int c = 0; c < 9; ++c) {
            const int ch = wv * 9 + c;               // 0..71
            const int a  = (ch >= 36) ? 1 : 0;       // 0: out, 1: tgt
            const int rh = ch - a * 36;              // 0..35
            const int r  = rh >> 1;                  // LDS row 0..17
            const int hf = rh & 1;                   // 1KB half of the row
            const int gr = min(max(y0s - 1 + r, 0), HH - 1);   // clamped
            const float* src = (a ? tgt_img : out_img) + base
                             + (size_t)gr * WW + hf * 256 + lane * 4;
            float* dst = &tile[buf][a][r * WW + hf * 256 + lane * 4];
            async_copy16(src, dst);
        }
    };

#define ROWLOAD(dst, lr) {                                                     \
    const float4 o4 = *(const float4*)&ot[(lr) * WW + cb];                     \
    const float4 t4 = *(const float4*)&tt[(lr) * WW + cb];                     \
    const float m_ = ((unsigned)(y0s - 1 + (lr)) < (unsigned)HH) ? 1.f : 0.f;  \
    dst = make_float4(m_*(t4.x-o4.x), m_*(t4.y-o4.y),                          \
                      m_*(t4.z-o4.z), m_*(t4.w-o4.w));                         }
#define ROWPASS(hs, hd, d, lr) {                                               \
    const float svL = __shfl(s255, (lr), 64);                                  \
    const float svR = __shfl(s256, (lr), 64);                                  \
    float dl = __shfl_up((d).w, 1, 64);                                        \
    float dr = __shfl_down((d).x, 1, 64);                                      \
    if (lane == 0)  dl = h ? svL : 0.f;                                        \
    if (lane == 63) dr = h ? 0.f : svR;                                        \
    hs.x = fmaf(2.f, (d).x, dl + (d).y);      hd.x = (d).y - dl;               \
    hs.y = fmaf(2.f, (d).y, (d).x + (d).z);   hd.y = (d).z - (d).x;            \
    hs.z = fmaf(2.f, (d).z, (d).y + (d).w);   hd.z = (d).w - (d).y;            \
    hs.w = fmaf(2.f, (d).w, (d).z + dr);      hd.w = dr - (d).z;               }
#define ACCUM(hsT, hdT, hsM, hdM, hsB, hdB) {                                  \
    float gx, gy;                                                              \
    gx = fmaf(2.f, hdM.x, hdT.x + hdB.x); gy = hsT.x - hsB.x;                  \
    acc = fmaf(gx, gx, acc); acc = fmaf(gy, gy, acc);                          \
    gx = fmaf(2.f, hdM.y, hdT.y + hdB.y); gy = hsT.y - hsB.y;                  \
    acc = fmaf(gx, gx, acc); acc = fmaf(gy, gy, acc);                          \
    gx = fmaf(2.f, hdM.z, hdT.z + hdB.z); gy = hsT.z - hsB.z;                  \
    acc = fmaf(gx, gx, acc); acc = fmaf(gy, gy, acc);                          \
    gx = fmaf(2.f, hdM.w, hdT.w + hdB.w); gy = hsT.w - hsB.w;                  \
    acc = fmaf(gx, gx, acc); acc = fmaf(gy, gy, acc);                          }

    float acc = 0.f;
    STAGE(0, strip0);

    #pragma unroll
    for (int t = 0; t < 4; ++t) {
        if (t < 3) STAGE((t + 1) & 1, strip0 + t + 1);

        // counted drain: wait ONLY for tile t's 9 chunks; tile t+1's stay
        // in flight across the barrier and drain under compute (T4).
        if (t < 3) { asm volatile("s_waitcnt vmcnt(9)" ::: "memory"); }
        else       { asm volatile("s_waitcnt vmcnt(0)" ::: "memory"); }
        __builtin_amdgcn_s_barrier();
        __builtin_amdgcn_sched_barrier(0);

        {   // ---- compute tile t from buf[t&1] ----
            const int y0s = (strip0 + t) * TR;
            const float* ot = &tile[t & 1][0][0];
            const float* tt = &tile[t & 1][1][0];
            const int lr0 = 2 * wv;              // LDS rows lr0..lr0+3

            float s255 = 0.f, s256 = 0.f;        // seam d-values, masked
            if (lane < NRW) {
                const float m_ = ((unsigned)(y0s - 1 + lane) < (unsigned)HH)
                               ? 1.f : 0.f;
                s255 = m_ * (tt[lane * WW + 255] - ot[lane * WW + 255]);
                s256 = m_ * (tt[lane * WW + 256] - ot[lane * WW + 256]);
            }
            #pragma unroll
            for (int h = 0; h < 2; ++h) {
                const int cb = (h << 8) + lane * 4;   // lane*16B: conflict-free
                float4 d0, d1, d2;
                float4 hs0, hd0, hs1, hd1, hs2, hd2;
                ROWLOAD(d0, lr0 + 0); ROWPASS(hs0, hd0, d0, lr0 + 0);
                ROWLOAD(d1, lr0 + 1); ROWPASS(hs1, hd1, d1, lr0 + 1);
                ROWLOAD(d2, lr0 + 2); ROWPASS(hs2, hd2, d2, lr0 + 2);
                ACCUM(hs0, hd0, hs1, hd1, hs2, hd2);
                ROWLOAD(d0, lr0 + 3); ROWPASS(hs0, hd0, d0, lr0 + 3);
                ACCUM(hs1, hd1, hs2, hd2, hs0, hd0);
            }
        }

        // all waves done READING buf[t&1] before iter t+1 overwrites it.
        // (each wave's ds_reads are complete here via their VALU uses)
        __builtin_amdgcn_sched_barrier(0);
        __builtin_amdgcn_s_barrier();
    }
#undef ROWLOAD
#undef ROWPASS
#undef ACCUM

    // ---- wave reduce -> block reduce -> one plain store per block ----
    #pragma unroll
    for (int off = 32; off > 0; off >>= 1)
        acc += __shfl_down(acc, off, 64);
    if (lane == 0) wsum[wv] = acc;
    __syncthreads();
    if (tid == 0) {
        float s = 0.f;
        #pragma unroll
        for (int k = 0; k < TPB / 64; ++k) s += wsum[k];
        partials[b] = s;
    }
}

__global__ __launch_bounds__(256) void reduce_partials_kernel(
    const float* __restrict__ partials, float* __restrict__ out)
{
    const int tid = threadIdx.x;
    float s = partials[tid];                   // 256 partials, 256 threads
    #pragma unroll
    for (int off = 32; off > 0; off >>= 1)
        s += __shfl_down(s, off, 64);
    __shared__ float wsum[4];
    if ((tid & 63) == 0) wsum[tid >> 6] = s;
    __syncthreads();
    if (tid == 0)
        out[0] = (wsum[0] + wsum[1] + wsum[2] + wsum[3])
               * (1.0f / ((float)BATCH * HH * WW));
}

extern "C" void kernel_launch(void* const* d_in, const int* in_sizes, int n_in,
                              void* d_out, int out_size, void* d_ws, size_t ws_size,
                              hipStream_t stream) {
    (void)in_sizes; (void)n_in; (void)ws_size; (void)out_size;
    const float* out_img = (const float*)d_in[0];   // "output"
    const float* tgt_img = (const float*)d_in[1];   // "target"
    float* partials = (float*)d_ws;                 // NBLK floats, overwritten
    float* res = (float*)d_out;

    sobel_partial_kernel<<<NBLK, TPB, 0, stream>>>(out_img, tgt_img, partials);
    reduce_partials_kernel<<<1, 256, 0, stream>>>(partials, res);
}